// Round 15
// baseline (341.961 us; speedup 1.0000x reference)
//
#include <hip/hip_runtime.h>
#include <hip/hip_bf16.h>

// GCN 2-layer forward, MI355X. F=512, H=16, C=32.
// ATTRIBUTION ROUND 2: k_gemm_mfma launched 3x (pure function, deterministic);
// dur_us - 240 (r12 baseline) = 2 x t(gemm). Aggs reverted to r12's 16-lane
// 8-unroll form (best measured). Everything else identical to r12.

#define BK 128
#define BKSH 7
#define MAXNB 1024
#define CHUNK 12800
#define SLAB 5120

typedef __attribute__((ext_vector_type(8))) short bf16x8;
typedef __attribute__((ext_vector_type(4))) float f32x4;

union ABpack { bf16x8 v; int i[4]; };

__device__ __forceinline__ int cvt2(float a, float b) {
    __hip_bfloat162 h = __float22bfloat162_rn(make_float2(a, b));
    return *reinterpret_cast<int*>(&h);
}
__device__ __forceinline__ unsigned short cvt1(float a) {
    __hip_bfloat16 h = __float2bfloat16(a);
    return *reinterpret_cast<unsigned short*>(&h);
}
__device__ __forceinline__ float b2f(unsigned short s) {
    return __uint_as_float(((unsigned)s) << 16);
}

__device__ __forceinline__ void load_lds16(const float* g, void* l) {
    __builtin_amdgcn_global_load_lds((const __attribute__((address_space(1))) void*)g,
                                     (__attribute__((address_space(3))) void*)l, 16, 0, 0);
}

__global__ __launch_bounds__(256) void k_init_cur(int* __restrict__ gcur, int NB) {
    int i = blockIdx.x * 256 + threadIdx.x;
    if (i < NB) gcur[i] = i * SLAB;
}

__global__ __launch_bounds__(256) void k_fill2(const int* __restrict__ src,
                                               const int* __restrict__ dst,
                                               int* __restrict__ gcur,
                                               int* __restrict__ gq, int E, int NB) {
    __shared__ int h[MAXNB];
    __shared__ int base[MAXNB];
    for (int t = threadIdx.x; t < NB; t += 256) h[t] = 0;
    __syncthreads();
    int e0 = blockIdx.x * CHUNK, e1 = min(E, e0 + CHUNK);
    for (int e = e0 + threadIdx.x; e < e1; e += 256)
        atomicAdd(&h[dst[e] >> BKSH], 1);
    __syncthreads();
    for (int t = threadIdx.x; t < NB; t += 256) {
        int c = h[t];
        base[t] = c ? atomicAdd(&gcur[t], c) : 0;
    }
    __syncthreads();
    for (int t = threadIdx.x; t < NB; t += 256) h[t] = 0;
    __syncthreads();
    for (int e = e0 + threadIdx.x; e < e1; e += 256) {
        int d = dst[e], b = d >> BKSH;
        int loc = atomicAdd(&h[b], 1);
        gq[base[b] + loc] = (src[e] << BKSH) | (d & (BK - 1));
    }
}

__global__ __launch_bounds__(256) void k_sortb(const int* __restrict__ gq,
                                               const int* __restrict__ gcur,
                                               int* __restrict__ gq2,
                                               int* __restrict__ offs,
                                               int* __restrict__ nend,
                                               float* __restrict__ dinv, int n) {
    __shared__ int cnt[BK];
    __shared__ int cur[BK];
    int b = blockIdx.x;
    int p0 = b * SLAB, p1 = gcur[b];
    if (threadIdx.x < BK) cnt[threadIdx.x] = 0;
    __syncthreads();
    for (int p = p0 + threadIdx.x; p < p1; p += 256)
        atomicAdd(&cnt[__builtin_nontemporal_load(gq + p) & (BK - 1)], 1);
    __syncthreads();
    if (threadIdx.x < BK) cur[threadIdx.x] = cnt[threadIdx.x];
    __syncthreads();
    for (int o = 1; o < BK; o <<= 1) {
        int v = (threadIdx.x < BK && threadIdx.x >= o) ? cur[threadIdx.x - o] : 0;
        __syncthreads();
        if (threadIdx.x < BK) cur[threadIdx.x] += v;
        __syncthreads();
    }
    if (threadIdx.x < BK) {
        int c = cnt[threadIdx.x];
        int excl = cur[threadIdx.x] - c;
        int node = (b << BKSH) + threadIdx.x;
        if (node < n) {
            offs[node] = p0 + excl;
            nend[node] = p0 + excl + c;
            dinv[node] = rsqrtf((float)(c + 1));
        }
        cur[threadIdx.x] = excl;
    }
    __syncthreads();
    for (int p = p0 + threadIdx.x; p < p1; p += 256) {
        int e = __builtin_nontemporal_load(gq + p);
        int loc = atomicAdd(&cur[e & (BK - 1)], 1);
        gq2[p0 + loc] = e >> BKSH;
    }
}

__global__ __launch_bounds__(256) void k_gemm_mfma(const float* __restrict__ x,
                                                   const float* __restrict__ W1,
                                                   const float* __restrict__ dinv,
                                                   unsigned short* __restrict__ gs1,
                                                   int n) {
    const int lane = threadIdx.x & 63;
    const int r = lane & 15;
    const int g4 = lane >> 4;
    const int wid = blockIdx.x * 4 + (threadIdx.x >> 6);
    const int nw = gridDim.x * 4;

    ABpack wf[16];
#pragma unroll
    for (int s = 0; s < 16; ++s) {
        int kb = s * 32 + g4 * 8;
#pragma unroll
        for (int j = 0; j < 4; ++j)
            wf[s].i[j] = cvt2(W1[(size_t)(kb + 2 * j) * 16 + r],
                              W1[(size_t)(kb + 2 * j + 1) * 16 + r]);
    }

    const int ntiles = (n + 15) >> 4;
    for (int tile = wid; tile < ntiles; tile += nw) {
        int m0 = tile << 4;
        int arow = m0 + r;
        if (arow >= n) arow = n - 1;
        const float* xp = x + (size_t)arow * 512 + g4 * 8;
        f32x4 acc = {0.f, 0.f, 0.f, 0.f};
#pragma unroll
        for (int s = 0; s < 16; ++s) {
            f32x4 f0 = __builtin_nontemporal_load(reinterpret_cast<const f32x4*>(xp + s * 32));
            f32x4 f1 = __builtin_nontemporal_load(reinterpret_cast<const f32x4*>(xp + s * 32 + 4));
            ABpack ah;
            ah.i[0] = cvt2(f0[0], f0[1]);
            ah.i[1] = cvt2(f0[2], f0[3]);
            ah.i[2] = cvt2(f1[0], f1[1]);
            ah.i[3] = cvt2(f1[2], f1[3]);
            acc = __builtin_amdgcn_mfma_f32_16x16x32_bf16(ah.v, wf[s].v, acc, 0, 0, 0);
        }
#pragma unroll
        for (int j = 0; j < 4; ++j) {
            int crow = m0 + g4 * 4 + j;
            if (crow < n) {
                float dvv = dinv[crow];
                gs1[(size_t)crow * 16 + r] = cvt1(acc[j] * dvv);
            }
        }
    }
}

__global__ __launch_bounds__(256) void k_agg_b(const unsigned short* __restrict__ featb,
                                               const int* __restrict__ gq2,
                                               const int* __restrict__ offs,
                                               const int* __restrict__ nend,
                                               const float* __restrict__ dinv,
                                               const float* __restrict__ bias,
                                               unsigned short* __restrict__ out_b,
                                               int n) {
    int t = blockIdx.x * 256 + threadIdx.x;
    int i = t >> 4, k = t & 15;
    if (i >= n) return;
    float acc = b2f(featb[(size_t)i * 16 + k]);
    int p = offs[i], p1 = nend[i];
    for (; p + 8 <= p1; p += 8) {
        int s0 = __builtin_nontemporal_load(gq2 + p);
        int s1 = __builtin_nontemporal_load(gq2 + p + 1);
        int s2 = __builtin_nontemporal_load(gq2 + p + 2);
        int s3 = __builtin_nontemporal_load(gq2 + p + 3);
        int s4 = __builtin_nontemporal_load(gq2 + p + 4);
        int s5 = __builtin_nontemporal_load(gq2 + p + 5);
        int s6 = __builtin_nontemporal_load(gq2 + p + 6);
        int s7 = __builtin_nontemporal_load(gq2 + p + 7);
        float v0 = b2f(featb[(size_t)s0 * 16 + k]);
        float v1 = b2f(featb[(size_t)s1 * 16 + k]);
        float v2 = b2f(featb[(size_t)s2 * 16 + k]);
        float v3 = b2f(featb[(size_t)s3 * 16 + k]);
        float v4 = b2f(featb[(size_t)s4 * 16 + k]);
        float v5 = b2f(featb[(size_t)s5 * 16 + k]);
        float v6 = b2f(featb[(size_t)s6 * 16 + k]);
        float v7 = b2f(featb[(size_t)s7 * 16 + k]);
        acc += ((v0 + v1) + (v2 + v3)) + ((v4 + v5) + (v6 + v7));
    }
    for (; p < p1; ++p)
        acc += b2f(featb[(size_t)__builtin_nontemporal_load(gq2 + p) * 16 + k]);
    float dvi = dinv[i];
    float v = fmaxf(dvi * acc + bias[k], 0.f) * dvi;
    out_b[(size_t)i * 16 + k] = cvt1(v);
}

__global__ __launch_bounds__(256) void k_agg_out(const unsigned short* __restrict__ featb,
                                                 const int* __restrict__ gq2,
                                                 const int* __restrict__ offs,
                                                 const int* __restrict__ nend,
                                                 const float* __restrict__ dinv,
                                                 const float* __restrict__ W2,
                                                 const float* __restrict__ b2,
                                                 float* __restrict__ out, int n) {
    __shared__ float Ws[16 * 33];
    __shared__ float bs[32];
    __shared__ float As[16][17];
    for (int t = threadIdx.x; t < 512; t += 256) Ws[(t >> 5) * 33 + (t & 31)] = W2[t];
    if (threadIdx.x < 32) bs[threadIdx.x] = b2[threadIdx.x];

    int t = blockIdx.x * 256 + threadIdx.x;
    int i = t >> 4, k = t & 15, nl = threadIdx.x >> 4;
    float acc = 0.f;
    if (i < n) {
        acc = b2f(featb[(size_t)i * 16 + k]);
        int p = offs[i], p1 = nend[i];
        for (; p + 8 <= p1; p += 8) {
            int s0 = __builtin_nontemporal_load(gq2 + p);
            int s1 = __builtin_nontemporal_load(gq2 + p + 1);
            int s2 = __builtin_nontemporal_load(gq2 + p + 2);
            int s3 = __builtin_nontemporal_load(gq2 + p + 3);
            int s4 = __builtin_nontemporal_load(gq2 + p + 4);
            int s5 = __builtin_nontemporal_load(gq2 + p + 5);
            int s6 = __builtin_nontemporal_load(gq2 + p + 6);
            int s7 = __builtin_nontemporal_load(gq2 + p + 7);
            float v0 = b2f(featb[(size_t)s0 * 16 + k]);
            float v1 = b2f(featb[(size_t)s1 * 16 + k]);
            float v2 = b2f(featb[(size_t)s2 * 16 + k]);
            float v3 = b2f(featb[(size_t)s3 * 16 + k]);
            float v4 = b2f(featb[(size_t)s4 * 16 + k]);
            float v5 = b2f(featb[(size_t)s5 * 16 + k]);
            float v6 = b2f(featb[(size_t)s6 * 16 + k]);
            float v7 = b2f(featb[(size_t)s7 * 16 + k]);
            acc += ((v0 + v1) + (v2 + v3)) + ((v4 + v5) + (v6 + v7));
        }
        for (; p < p1; ++p)
            acc += b2f(featb[(size_t)__builtin_nontemporal_load(gq2 + p) * 16 + k]);
        acc *= dinv[i];
    }
    As[nl][k] = acc;
    __syncthreads();
    if (i < n) {
        float v0 = bs[k], v1 = bs[k + 16];
#pragma unroll
        for (int kk = 0; kk < 16; ++kk) {
            float a = As[nl][kk];
            v0 += a * Ws[kk * 33 + k];
            v1 += a * Ws[kk * 33 + k + 16];
        }
        float m = fmaxf(v0, v1);
#pragma unroll
        for (int o = 8; o > 0; o >>= 1) m = fmaxf(m, __shfl_xor(m, o, 16));
        float pp = expf(v0 - m) + expf(v1 - m);
#pragma unroll
        for (int o = 8; o > 0; o >>= 1) pp += __shfl_xor(pp, o, 16);
        float lg = logf(pp);
        float* op = out + (size_t)i * 32;
        op[k] = v0 - m - lg;
        op[k + 16] = v1 - m - lg;
    }
}

// ---- fallback path kernels (atomic scatter, fp32) ----
__global__ __launch_bounds__(256) void k_zero_i(int* __restrict__ p, int n) {
    int i = blockIdx.x * 256 + threadIdx.x;
    if (i < n) p[i] = 0;
}

__global__ __launch_bounds__(256) void k_count(const int* __restrict__ dst,
                                               int* __restrict__ cnt, int E) {
    int e = blockIdx.x * 256 + threadIdx.x;
    if (e < E) atomicAdd(&cnt[dst[e]], 1);
}

__global__ __launch_bounds__(256) void k_dinv(const int* __restrict__ cnt,
                                              float* __restrict__ dinv, int n) {
    int i = blockIdx.x * 256 + threadIdx.x;
    if (i < n) dinv[i] = rsqrtf((float)(cnt[i] + 1));
}

__global__ __launch_bounds__(256) void k_gemm1(const float* __restrict__ x,
                                               const float* __restrict__ W1,
                                               const float* __restrict__ dinv,
                                               float* __restrict__ h1,
                                               float* __restrict__ r1self, int n) {
    __shared__ float Ws[8192];
    __shared__ float4 Xs[4][512];
    for (int t = threadIdx.x; t < 8192; t += 256) {
        int sa = t ^ (((t >> 9) & 1) << 4);
        Ws[sa] = W1[t];
    }
    __syncthreads();
    const int wave = threadIdx.x >> 6;
    const int lane = threadIdx.x & 63;
    const int q = lane & 15, g = lane >> 4;
    const int sr = lane >> 3, su = lane & 7;
    const int first = blockIdx.x * 4 + wave;
    const int stride = gridDim.x * 4;
    const int ngroups = (n + 7) >> 3;
    if (first >= ngroups) return;
    const int mygroups = (ngroups - first + stride - 1) / stride;
    const int T = mygroups * 4;
    char* xbase = (char*)(&Xs[wave][0]);
    auto stage = [&](int i) {
        int k = i >> 2, c = i & 3;
        int r0 = (first + k * stride) << 3;
        int row = r0 + sr;
        if (row >= n) row = n - 1;
        const float* gp = x + (size_t)row * 512 + c * 128 + su * 4;
        char* lb = xbase + (i & 1) * 4096;
#pragma unroll
        for (int m = 0; m < 4; ++m) load_lds16(gp + m * 32, lb + m * 1024);
    };
    stage(0);
    if (T > 1) stage(1);
    int issued = (T > 1) ? 2 : 1;
    float acc[8];
    const float4* xw = &Xs[wave][0];
    const int flip = (g & 1) << 4;
    for (int i = 0; i < T; ++i) {
        if (i < T - 1) asm volatile("s_waitcnt vmcnt(4)" ::: "memory");
        else           asm volatile("s_waitcnt vmcnt(0)" ::: "memory");
        int c = i & 3;
        const float4* xb = xw + (i & 1) * 256;
        if (c == 0) {
#pragma unroll
            for (int r = 0; r < 8; ++r) acc[r] = 0.f;
        }
        const int aW = 2048 * c + 512 * g + q;
#pragma unroll
        for (int t = 0; t < 8; ++t) {
            int tg = (t + g) & 7;
            float4 xv[8];
#pragma unroll
            for (int r = 0; r < 8; ++r) xv[r] = xb[g * 64 + r * 8 + tg];
            int a0 = aW + 64 * tg;
            float w0 = Ws[(a0) ^ flip];
            float w1 = Ws[(a0 + 16) ^ flip];
            float w2 = Ws[(a0 + 32) ^ flip];
            float w3 = Ws[(a0 + 48) ^ flip];
#pragma unroll
            for (int r = 0; r < 8; ++r)
                acc[r] += xv[r].x * w0 + xv[r].y * w1 + xv[r].z * w2 + xv[r].w * w3;
        }
        if (issued < T) { stage(issued); ++issued; }
        if (c == 3) {
            int r0 = (first + (i >> 2) * stride) << 3;
#pragma unroll
            for (int r = 0; r < 8; ++r) {
                acc[r] += __shfl_xor(acc[r], 16);
                acc[r] += __shfl_xor(acc[r], 32);
            }
            float v0 = 0.f, v1 = 0.f;
#pragma unroll
            for (int r = 0; r < 4; ++r)
                if (g == r) { v0 = acc[r]; v1 = acc[r + 4]; }
            int row0 = r0 + g, row1 = r0 + 4 + g;
            if (row0 < n) {
                h1[(size_t)row0 * 16 + q] = v0;
                if (r1self) { float dv = dinv[row0]; r1self[(size_t)row0 * 16 + q] = v0 * dv * dv; }
            }
            if (row1 < n) {
                h1[(size_t)row1 * 16 + q] = v1;
                if (r1self) { float dv = dinv[row1]; r1self[(size_t)row1 * 16 + q] = v1 * dv * dv; }
            }
        }
    }
}

__global__ __launch_bounds__(256) void k_scatter16(const int* __restrict__ src,
                                                   const int* __restrict__ dst,
                                                   const float* __restrict__ feat,
                                                   const float* __restrict__ dinv,
                                                   float* __restrict__ outf, int total) {
    int t = blockIdx.x * 256 + threadIdx.x;
    if (t >= total) return;
    int e = t >> 4, k = t & 15;
    int s = src[e], d = dst[e];
    float w = dinv[s] * dinv[d];
    unsafeAtomicAdd(&outf[(size_t)d * 16 + k], feat[(size_t)s * 16 + k] * w);
}

__global__ __launch_bounds__(256) void k_relu16(float* __restrict__ r1,
                                                const float* __restrict__ b1, int total) {
    int t = blockIdx.x * 256 + threadIdx.x;
    if (t < total) r1[t] = fmaxf(r1[t] + b1[t & 15], 0.f);
}

__global__ __launch_bounds__(256) void k_self16(const float* __restrict__ feat,
                                                const float* __restrict__ dinv,
                                                float* __restrict__ outf, int total) {
    int t = blockIdx.x * 256 + threadIdx.x;
    if (t >= total) return;
    float dv = dinv[t >> 4];
    outf[t] = feat[t] * dv * dv;
}

__global__ __launch_bounds__(256) void k_out(const float* __restrict__ a,
                                             const float* __restrict__ W2,
                                             const float* __restrict__ b2,
                                             float* __restrict__ out, int n) {
    __shared__ float Ws[16 * 33];
    __shared__ float bs[32];
    for (int t = threadIdx.x; t < 512; t += 256) Ws[(t >> 5) * 33 + (t & 31)] = W2[t];
    if (threadIdx.x < 32) bs[threadIdx.x] = b2[threadIdx.x];
    __syncthreads();
    int t = blockIdx.x * 256 + threadIdx.x;
    int i = t >> 5, c = t & 31;
    if (i >= n) return;
    const float4* ar = reinterpret_cast<const float4*>(a + (size_t)i * 16);
    float acc = bs[c];
#pragma unroll
    for (int kk = 0; kk < 4; ++kk) {
        float4 v = ar[kk];
        acc += v.x * Ws[(4 * kk + 0) * 33 + c];
        acc += v.y * Ws[(4 * kk + 1) * 33 + c];
        acc += v.z * Ws[(4 * kk + 2) * 33 + c];
        acc += v.w * Ws[(4 * kk + 3) * 33 + c];
    }
    float m = acc;
#pragma unroll
    for (int o = 16; o > 0; o >>= 1) m = fmaxf(m, __shfl_xor(m, o, 32));
    float p = expf(acc - m);
#pragma unroll
    for (int o = 16; o > 0; o >>= 1) p += __shfl_xor(p, o, 32);
    out[t] = acc - m - logf(p);
}

extern "C" void kernel_launch(void* const* d_in, const int* in_sizes, int n_in,
                              void* d_out, int out_size, void* d_ws, size_t ws_size,
                              hipStream_t stream) {
    const float* x  = (const float*)d_in[0];
    const int* ei   = (const int*)d_in[1];
    const float* W1 = (const float*)d_in[2];
    const float* b1 = (const float*)d_in[3];
    const float* W2 = (const float*)d_in[4];
    const float* b2 = (const float*)d_in[5];
    float* out = (float*)d_out;

    const int n = in_sizes[0] / 512;
    const int E = in_sizes[1] / 2;
    const int* src = ei;
    const int* dst = ei + E;
    const int NB = (n + BK - 1) >> BKSH;
    const int gfill = (E + CHUNK - 1) / CHUNK;
    const int ntiles = (n + 15) >> 4;
    const int ggemm = (ntiles + 3) / 4;

    float* ws = (float*)d_ws;

    size_t u_dinv  = 0;
    size_t u_foffs = u_dinv + n;
    size_t u_nend  = u_foffs + n;
    size_t u_gcur  = u_nend + n;
    size_t u_gq    = u_gcur + NB;
    size_t u_gq2   = u_gq + (size_t)NB * SLAB;
    size_t u_h1    = u_gq2 + (size_t)NB * SLAB;
    size_t u_r1    = u_h1 + 16 * (size_t)n;
    size_t need    = (u_r1 + 16 * (size_t)n) * 4;

    if (ws_size >= need && NB <= MAXNB) {
        float* dinv = ws + u_dinv;
        int* offs   = (int*)(ws + u_foffs);
        int* nend   = (int*)(ws + u_nend);
        int* gcur   = (int*)(ws + u_gcur);
        int* gq     = (int*)(ws + u_gq);
        int* gq2    = (int*)(ws + u_gq2);
        unsigned short* gs1b = (unsigned short*)(ws + u_h1);
        unsigned short* r1sb = (unsigned short*)(ws + u_r1);

        k_init_cur<<<(NB + 255) / 256, 256, 0, stream>>>(gcur, NB);
        k_fill2   <<<gfill, 256, 0, stream>>>(src, dst, gcur, gq, E, NB);
        k_sortb   <<<NB, 256, 0, stream>>>(gq, gcur, gq2, offs, nend, dinv, n);
        // ATTRIBUTION: gemm x3 (pure function; extra launches are semantic
        // no-ops). dur_us - 240 = 2 * t(gemm).
        k_gemm_mfma<<<ggemm, 256, 0, stream>>>(x, W1, dinv, gs1b, n);
        k_gemm_mfma<<<ggemm, 256, 0, stream>>>(x, W1, dinv, gs1b, n);
        k_gemm_mfma<<<ggemm, 256, 0, stream>>>(x, W1, dinv, gs1b, n);
        k_agg_b   <<<(n * 16 + 255) / 256, 256, 0, stream>>>(gs1b, gq2, offs, nend,
                                                             dinv, b1, r1sb, n);
        k_agg_out <<<(n * 16 + 255) / 256, 256, 0, stream>>>(r1sb, gq2, offs, nend,
                                                             dinv, W2, b2, out, n);
    } else {
        float* dinv = ws;
        float* h1   = ws + n;
        float* r1   = ws + n + 16 * (size_t)n;
        int* cnt    = (int*)h1;
        float* agg2r = h1;

        const int total1 = E * 16;
        k_zero_i   <<<(n + 255) / 256, 256, 0, stream>>>(cnt, n);
        k_count    <<<(E + 255) / 256, 256, 0, stream>>>(dst, cnt, E);
        k_dinv     <<<(n + 255) / 256, 256, 0, stream>>>(cnt, dinv, n);
        k_gemm1    <<<1024, 256, 0, stream>>>(x, W1, dinv, h1, r1, n);
        k_scatter16<<<(total1 + 255) / 256, 256, 0, stream>>>(src, dst, h1, dinv, r1, total1);
        k_relu16   <<<(n * 16 + 255) / 256, 256, 0, stream>>>(r1, b1, n * 16);
        k_self16   <<<(n * 16 + 255) / 256, 256, 0, stream>>>(r1, dinv, agg2r, n * 16);
        k_scatter16<<<(total1 + 255) / 256, 256, 0, stream>>>(src, dst, r1, dinv, agg2r, total1);
        k_out      <<<(n * 32 + 255) / 256, 256, 0, stream>>>(agg2r, W2, b2, out, n);
    }
}

// Round 16
// 249.168 us; speedup vs baseline: 1.3724x; 1.3724x over previous
//
#include <hip/hip_runtime.h>
#include <hip/hip_bf16.h>

// GCN 2-layer forward, MI355X. F=512, H=16, C=32.
// Slab binning -> per-bucket counting sort -> fine CSR -> 16-lane gather aggs
// over bf16 dinv-prescaled tables (measured floor). gemm v3: block-cooperative
// LDS-staged MFMA (contiguous 32KB tile streaming, swizzled source, counted
// vmcnt + raw barriers, K split across waves + LDS reduce).

#define BK 128
#define BKSH 7
#define MAXNB 1024
#define CHUNK 3200
#define SLAB 5120

typedef __attribute__((ext_vector_type(8))) short bf16x8;
typedef __attribute__((ext_vector_type(4))) float f32x4;

union ABpack { bf16x8 v; int i[4]; };

__device__ __forceinline__ int cvt2(float a, float b) {
    __hip_bfloat162 h = __float22bfloat162_rn(make_float2(a, b));
    return *reinterpret_cast<int*>(&h);
}
__device__ __forceinline__ unsigned short cvt1(float a) {
    __hip_bfloat16 h = __float2bfloat16(a);
    return *reinterpret_cast<unsigned short*>(&h);
}
__device__ __forceinline__ float b2f(unsigned short s) {
    return __uint_as_float(((unsigned)s) << 16);
}

__device__ __forceinline__ void load_lds16(const float* g, void* l) {
    __builtin_amdgcn_global_load_lds((const __attribute__((address_space(1))) void*)g,
                                     (__attribute__((address_space(3))) void*)l, 16, 0, 0);
}

__global__ __launch_bounds__(256) void k_init_cur(int* __restrict__ gcur, int NB) {
    int i = blockIdx.x * 256 + threadIdx.x;
    if (i < NB) gcur[i] = i * SLAB;
}

__global__ __launch_bounds__(256) void k_fill2(const int* __restrict__ src,
                                               const int* __restrict__ dst,
                                               int* __restrict__ gcur,
                                               int* __restrict__ gq, int E, int NB) {
    __shared__ int h[MAXNB];
    __shared__ int base[MAXNB];
    for (int t = threadIdx.x; t < NB; t += 256) h[t] = 0;
    __syncthreads();
    int e0 = blockIdx.x * CHUNK, e1 = min(E, e0 + CHUNK);
    for (int e = e0 + threadIdx.x; e < e1; e += 256)
        atomicAdd(&h[dst[e] >> BKSH], 1);
    __syncthreads();
    for (int t = threadIdx.x; t < NB; t += 256) {
        int c = h[t];
        base[t] = c ? atomicAdd(&gcur[t], c) : 0;
    }
    __syncthreads();
    for (int t = threadIdx.x; t < NB; t += 256) h[t] = 0;
    __syncthreads();
    for (int e = e0 + threadIdx.x; e < e1; e += 256) {
        int d = dst[e], b = d >> BKSH;
        int loc = atomicAdd(&h[b], 1);
        gq[base[b] + loc] = (src[e] << BKSH) | (d & (BK - 1));
    }
}

__global__ __launch_bounds__(256) void k_sortb(const int* __restrict__ gq,
                                               const int* __restrict__ gcur,
                                               int* __restrict__ gq2,
                                               int* __restrict__ offs,
                                               int* __restrict__ nend,
                                               float* __restrict__ dinv, int n) {
    __shared__ int cnt[BK];
    __shared__ int cur[BK];
    int b = blockIdx.x;
    int p0 = b * SLAB, p1 = gcur[b];
    if (threadIdx.x < BK) cnt[threadIdx.x] = 0;
    __syncthreads();
    for (int p = p0 + threadIdx.x; p < p1; p += 256)
        atomicAdd(&cnt[__builtin_nontemporal_load(gq + p) & (BK - 1)], 1);
    __syncthreads();
    if (threadIdx.x < BK) cur[threadIdx.x] = cnt[threadIdx.x];
    __syncthreads();
    for (int o = 1; o < BK; o <<= 1) {
        int v = (threadIdx.x < BK && threadIdx.x >= o) ? cur[threadIdx.x - o] : 0;
        __syncthreads();
        if (threadIdx.x < BK) cur[threadIdx.x] += v;
        __syncthreads();
    }
    if (threadIdx.x < BK) {
        int c = cnt[threadIdx.x];
        int excl = cur[threadIdx.x] - c;
        int node = (b << BKSH) + threadIdx.x;
        if (node < n) {
            offs[node] = p0 + excl;
            nend[node] = p0 + excl + c;
            dinv[node] = rsqrtf((float)(c + 1));
        }
        cur[threadIdx.x] = excl;
    }
    __syncthreads();
    for (int p = p0 + threadIdx.x; p < p1; p += 256) {
        int e = __builtin_nontemporal_load(gq + p);
        int loc = atomicAdd(&cur[e & (BK - 1)], 1);
        gq2[p0 + loc] = e >> BKSH;
    }
}

// gemm v3: block stages one 16-row (32KB, contiguous) x-tile into LDS, dbuf,
// K split across 4 waves (128 cols each), LDS reduce, wave0 epilogue.
// Swizzle: LDS byte o holds global byte o ^ (((o>>11)&7)<<4) (involution).
__global__ __launch_bounds__(256) void k_gemm_mfma(const float* __restrict__ x,
                                                   const float* __restrict__ W1,
                                                   const float* __restrict__ dinv,
                                                   unsigned short* __restrict__ gs1,
                                                   int n) {
    __shared__ char Xs[2][32768];
    __shared__ f32x4 red[256];
    const int tid = threadIdx.x;
    const int w = tid >> 6;
    const int lane = tid & 63;
    const int r = lane & 15;
    const int g4 = lane >> 4;

    // per-wave K-quarter W fragments (global s = w*4 + sl)
    ABpack wf[4];
#pragma unroll
    for (int sl = 0; sl < 4; ++sl) {
        int kb = (w * 4 + sl) * 32 + g4 * 8;
#pragma unroll
        for (int j = 0; j < 4; ++j)
            wf[sl].i[j] = cvt2(W1[(size_t)(kb + 2 * j) * 16 + r],
                               W1[(size_t)(kb + 2 * j + 1) * 16 + r]);
    }
    asm volatile("s_waitcnt vmcnt(0)" ::: "memory");

    auto stage = [&](int tile, int buf) {
        const char* gp = (const char*)x + (size_t)tile * 32768;
        char* lb = &Xs[buf][0];
#pragma unroll
        for (int c = 0; c < 8; ++c) {
            int o = c * 4096 + tid * 16;
            int g = o ^ (((o >> 11) & 7) << 4);
            load_lds16((const float*)(gp + g), lb + o);
        }
    };

    const int ntf = n >> 4;   // full tiles
    int tile = blockIdx.x;
    const int stride = gridDim.x;
    if (tile < ntf) stage(tile, 0);
    int buf = 0;
    const int swz = (r & 7) << 4;

    for (; tile < ntf; tile += stride) {
        int nxt = tile + stride;
        if (nxt < ntf) {
            stage(nxt, buf ^ 1);
            asm volatile("s_waitcnt vmcnt(8)" ::: "memory");
        } else {
            asm volatile("s_waitcnt vmcnt(0)" ::: "memory");
        }
        __builtin_amdgcn_s_barrier();   // cur tile fully staged (all threads)
        const char* lb = &Xs[buf][0];
        f32x4 acc = {0.f, 0.f, 0.f, 0.f};
#pragma unroll
        for (int sl = 0; sl < 4; ++sl) {
            int byte0 = r * 2048 + (w * 4 + sl) * 128 + g4 * 32;
            f32x4 f0 = *reinterpret_cast<const f32x4*>(lb + (byte0 ^ swz));
            f32x4 f1 = *reinterpret_cast<const f32x4*>(lb + ((byte0 + 16) ^ swz));
            ABpack ah;
            ah.i[0] = cvt2(f0[0], f0[1]);
            ah.i[1] = cvt2(f0[2], f0[3]);
            ah.i[2] = cvt2(f1[0], f1[1]);
            ah.i[3] = cvt2(f1[2], f1[3]);
            acc = __builtin_amdgcn_mfma_f32_16x16x32_bf16(ah.v, wf[sl].v, acc, 0, 0, 0);
        }
        red[tid] = acc;
        asm volatile("s_waitcnt lgkmcnt(0)" ::: "memory");
        __builtin_amdgcn_s_barrier();   // red complete; also: all Xs[buf] reads done
        if (w == 0) {
            f32x4 s0 = red[lane];
            f32x4 s1 = red[64 + lane];
            f32x4 s2 = red[128 + lane];
            f32x4 s3 = red[192 + lane];
            int m0 = tile << 4;
#pragma unroll
            for (int j = 0; j < 4; ++j) {
                int crow = m0 + g4 * 4 + j;
                float v = (s0[j] + s1[j]) + (s2[j] + s3[j]);
                gs1[(size_t)crow * 16 + r] = cvt1(v * dinv[crow]);
            }
        }
        buf ^= 1;
    }

    // tail (n % 16 != 0): direct clamped path, block 0 only. Unused for n=100000.
    if ((n & 15) && blockIdx.x == 0 && w == 0) {
        int m0 = ntf << 4;
        int arow = m0 + r;
        if (arow >= n) arow = n - 1;
        const float* xp = x + (size_t)arow * 512 + g4 * 8;
        // full-K accumulation on one wave: iterate all 16 s with wf reloaded
        f32x4 acc = {0.f, 0.f, 0.f, 0.f};
#pragma unroll
        for (int s = 0; s < 16; ++s) {
            ABpack wfl;
            int kb = s * 32 + g4 * 8;
#pragma unroll
            for (int j = 0; j < 4; ++j)
                wfl.i[j] = cvt2(W1[(size_t)(kb + 2 * j) * 16 + r],
                                W1[(size_t)(kb + 2 * j + 1) * 16 + r]);
            f32x4 f0 = *reinterpret_cast<const f32x4*>(xp + s * 32);
            f32x4 f1 = *reinterpret_cast<const f32x4*>(xp + s * 32 + 4);
            ABpack ah;
            ah.i[0] = cvt2(f0[0], f0[1]);
            ah.i[1] = cvt2(f0[2], f0[3]);
            ah.i[2] = cvt2(f1[0], f1[1]);
            ah.i[3] = cvt2(f1[2], f1[3]);
            acc = __builtin_amdgcn_mfma_f32_16x16x32_bf16(ah.v, wfl.v, acc, 0, 0, 0);
        }
#pragma unroll
        for (int j = 0; j < 4; ++j) {
            int crow = m0 + g4 * 4 + j;
            if (crow < n) {
                float dvv = dinv[crow];
                gs1[(size_t)crow * 16 + r] = cvt1(acc[j] * dvv);
            }
        }
    }
}

__global__ __launch_bounds__(256) void k_agg_b(const unsigned short* __restrict__ featb,
                                               const int* __restrict__ gq2,
                                               const int* __restrict__ offs,
                                               const int* __restrict__ nend,
                                               const float* __restrict__ dinv,
                                               const float* __restrict__ bias,
                                               unsigned short* __restrict__ out_b,
                                               int n) {
    int t = blockIdx.x * 256 + threadIdx.x;
    int i = t >> 4, k = t & 15;
    if (i >= n) return;
    float acc = b2f(featb[(size_t)i * 16 + k]);
    int p = offs[i], p1 = nend[i];
    for (; p + 8 <= p1; p += 8) {
        int s0 = __builtin_nontemporal_load(gq2 + p);
        int s1 = __builtin_nontemporal_load(gq2 + p + 1);
        int s2 = __builtin_nontemporal_load(gq2 + p + 2);
        int s3 = __builtin_nontemporal_load(gq2 + p + 3);
        int s4 = __builtin_nontemporal_load(gq2 + p + 4);
        int s5 = __builtin_nontemporal_load(gq2 + p + 5);
        int s6 = __builtin_nontemporal_load(gq2 + p + 6);
        int s7 = __builtin_nontemporal_load(gq2 + p + 7);
        float v0 = b2f(featb[(size_t)s0 * 16 + k]);
        float v1 = b2f(featb[(size_t)s1 * 16 + k]);
        float v2 = b2f(featb[(size_t)s2 * 16 + k]);
        float v3 = b2f(featb[(size_t)s3 * 16 + k]);
        float v4 = b2f(featb[(size_t)s4 * 16 + k]);
        float v5 = b2f(featb[(size_t)s5 * 16 + k]);
        float v6 = b2f(featb[(size_t)s6 * 16 + k]);
        float v7 = b2f(featb[(size_t)s7 * 16 + k]);
        acc += ((v0 + v1) + (v2 + v3)) + ((v4 + v5) + (v6 + v7));
    }
    for (; p < p1; ++p)
        acc += b2f(featb[(size_t)__builtin_nontemporal_load(gq2 + p) * 16 + k]);
    float dvi = dinv[i];
    float v = fmaxf(dvi * acc + bias[k], 0.f) * dvi;
    out_b[(size_t)i * 16 + k] = cvt1(v);
}

__global__ __launch_bounds__(256) void k_agg_out(const unsigned short* __restrict__ featb,
                                                 const int* __restrict__ gq2,
                                                 const int* __restrict__ offs,
                                                 const int* __restrict__ nend,
                                                 const float* __restrict__ dinv,
                                                 const float* __restrict__ W2,
                                                 const float* __restrict__ b2,
                                                 float* __restrict__ out, int n) {
    __shared__ float Ws[16 * 33];
    __shared__ float bs[32];
    __shared__ float As[16][17];
    for (int t = threadIdx.x; t < 512; t += 256) Ws[(t >> 5) * 33 + (t & 31)] = W2[t];
    if (threadIdx.x < 32) bs[threadIdx.x] = b2[threadIdx.x];

    int t = blockIdx.x * 256 + threadIdx.x;
    int i = t >> 4, k = t & 15, nl = threadIdx.x >> 4;
    float acc = 0.f;
    if (i < n) {
        acc = b2f(featb[(size_t)i * 16 + k]);
        int p = offs[i], p1 = nend[i];
        for (; p + 8 <= p1; p += 8) {
            int s0 = __builtin_nontemporal_load(gq2 + p);
            int s1 = __builtin_nontemporal_load(gq2 + p + 1);
            int s2 = __builtin_nontemporal_load(gq2 + p + 2);
            int s3 = __builtin_nontemporal_load(gq2 + p + 3);
            int s4 = __builtin_nontemporal_load(gq2 + p + 4);
            int s5 = __builtin_nontemporal_load(gq2 + p + 5);
            int s6 = __builtin_nontemporal_load(gq2 + p + 6);
            int s7 = __builtin_nontemporal_load(gq2 + p + 7);
            float v0 = b2f(featb[(size_t)s0 * 16 + k]);
            float v1 = b2f(featb[(size_t)s1 * 16 + k]);
            float v2 = b2f(featb[(size_t)s2 * 16 + k]);
            float v3 = b2f(featb[(size_t)s3 * 16 + k]);
            float v4 = b2f(featb[(size_t)s4 * 16 + k]);
            float v5 = b2f(featb[(size_t)s5 * 16 + k]);
            float v6 = b2f(featb[(size_t)s6 * 16 + k]);
            float v7 = b2f(featb[(size_t)s7 * 16 + k]);
            acc += ((v0 + v1) + (v2 + v3)) + ((v4 + v5) + (v6 + v7));
        }
        for (; p < p1; ++p)
            acc += b2f(featb[(size_t)__builtin_nontemporal_load(gq2 + p) * 16 + k]);
        acc *= dinv[i];
    }
    As[nl][k] = acc;
    __syncthreads();
    if (i < n) {
        float v0 = bs[k], v1 = bs[k + 16];
#pragma unroll
        for (int kk = 0; kk < 16; ++kk) {
            float a = As[nl][kk];
            v0 += a * Ws[kk * 33 + k];
            v1 += a * Ws[kk * 33 + k + 16];
        }
        float m = fmaxf(v0, v1);
#pragma unroll
        for (int o = 8; o > 0; o >>= 1) m = fmaxf(m, __shfl_xor(m, o, 16));
        float pp = expf(v0 - m) + expf(v1 - m);
#pragma unroll
        for (int o = 8; o > 0; o >>= 1) pp += __shfl_xor(pp, o, 16);
        float lg = logf(pp);
        float* op = out + (size_t)i * 32;
        op[k] = v0 - m - lg;
        op[k + 16] = v1 - m - lg;
    }
}

// ---- fallback path kernels (atomic scatter, fp32) ----
__global__ __launch_bounds__(256) void k_zero_i(int* __restrict__ p, int n) {
    int i = blockIdx.x * 256 + threadIdx.x;
    if (i < n) p[i] = 0;
}

__global__ __launch_bounds__(256) void k_count(const int* __restrict__ dst,
                                               int* __restrict__ cnt, int E) {
    int e = blockIdx.x * 256 + threadIdx.x;
    if (e < E) atomicAdd(&cnt[dst[e]], 1);
}

__global__ __launch_bounds__(256) void k_dinv(const int* __restrict__ cnt,
                                              float* __restrict__ dinv, int n) {
    int i = blockIdx.x * 256 + threadIdx.x;
    if (i < n) dinv[i] = rsqrtf((float)(cnt[i] + 1));
}

__global__ __launch_bounds__(256) void k_gemm1(const float* __restrict__ x,
                                               const float* __restrict__ W1,
                                               const float* __restrict__ dinv,
                                               float* __restrict__ h1,
                                               float* __restrict__ r1self, int n) {
    __shared__ float Ws[8192];
    __shared__ float4 Xs[4][512];
    for (int t = threadIdx.x; t < 8192; t += 256) {
        int sa = t ^ (((t >> 9) & 1) << 4);
        Ws[sa] = W1[t];
    }
    __syncthreads();
    const int wave = threadIdx.x >> 6;
    const int lane = threadIdx.x & 63;
    const int q = lane & 15, g = lane >> 4;
    const int sr = lane >> 3, su = lane & 7;
    const int first = blockIdx.x * 4 + wave;
    const int stride = gridDim.x * 4;
    const int ngroups = (n + 7) >> 3;
    if (first >= ngroups) return;
    const int mygroups = (ngroups - first + stride - 1) / stride;
    const int T = mygroups * 4;
    char* xbase = (char*)(&Xs[wave][0]);
    auto stage = [&](int i) {
        int k = i >> 2, c = i & 3;
        int r0 = (first + k * stride) << 3;
        int row = r0 + sr;
        if (row >= n) row = n - 1;
        const float* gp = x + (size_t)row * 512 + c * 128 + su * 4;
        char* lb = xbase + (i & 1) * 4096;
#pragma unroll
        for (int m = 0; m < 4; ++m) load_lds16(gp + m * 32, lb + m * 1024);
    };
    stage(0);
    if (T > 1) stage(1);
    int issued = (T > 1) ? 2 : 1;
    float acc[8];
    const float4* xw = &Xs[wave][0];
    const int flip = (g & 1) << 4;
    for (int i = 0; i < T; ++i) {
        if (i < T - 1) asm volatile("s_waitcnt vmcnt(4)" ::: "memory");
        else           asm volatile("s_waitcnt vmcnt(0)" ::: "memory");
        int c = i & 3;
        const float4* xb = xw + (i & 1) * 256;
        if (c == 0) {
#pragma unroll
            for (int r = 0; r < 8; ++r) acc[r] = 0.f;
        }
        const int aW = 2048 * c + 512 * g + q;
#pragma unroll
        for (int t = 0; t < 8; ++t) {
            int tg = (t + g) & 7;
            float4 xv[8];
#pragma unroll
            for (int r = 0; r < 8; ++r) xv[r] = xb[g * 64 + r * 8 + tg];
            int a0 = aW + 64 * tg;
            float w0 = Ws[(a0) ^ flip];
            float w1 = Ws[(a0 + 16) ^ flip];
            float w2 = Ws[(a0 + 32) ^ flip];
            float w3 = Ws[(a0 + 48) ^ flip];
#pragma unroll
            for (int r = 0; r < 8; ++r)
                acc[r] += xv[r].x * w0 + xv[r].y * w1 + xv[r].z * w2 + xv[r].w * w3;
        }
        if (issued < T) { stage(issued); ++issued; }
        if (c == 3) {
            int r0 = (first + (i >> 2) * stride) << 3;
#pragma unroll
            for (int r = 0; r < 8; ++r) {
                acc[r] += __shfl_xor(acc[r], 16);
                acc[r] += __shfl_xor(acc[r], 32);
            }
            float v0 = 0.f, v1 = 0.f;
#pragma unroll
            for (int r = 0; r < 4; ++r)
                if (g == r) { v0 = acc[r]; v1 = acc[r + 4]; }
            int row0 = r0 + g, row1 = r0 + 4 + g;
            if (row0 < n) {
                h1[(size_t)row0 * 16 + q] = v0;
                if (r1self) { float dv = dinv[row0]; r1self[(size_t)row0 * 16 + q] = v0 * dv * dv; }
            }
            if (row1 < n) {
                h1[(size_t)row1 * 16 + q] = v1;
                if (r1self) { float dv = dinv[row1]; r1self[(size_t)row1 * 16 + q] = v1 * dv * dv; }
            }
        }
    }
}

__global__ __launch_bounds__(256) void k_scatter16(const int* __restrict__ src,
                                                   const int* __restrict__ dst,
                                                   const float* __restrict__ feat,
                                                   const float* __restrict__ dinv,
                                                   float* __restrict__ outf, int total) {
    int t = blockIdx.x * 256 + threadIdx.x;
    if (t >= total) return;
    int e = t >> 4, k = t & 15;
    int s = src[e], d = dst[e];
    float w = dinv[s] * dinv[d];
    unsafeAtomicAdd(&outf[(size_t)d * 16 + k], feat[(size_t)s * 16 + k] * w);
}

__global__ __launch_bounds__(256) void k_relu16(float* __restrict__ r1,
                                                const float* __restrict__ b1, int total) {
    int t = blockIdx.x * 256 + threadIdx.x;
    if (t < total) r1[t] = fmaxf(r1[t] + b1[t & 15], 0.f);
}

__global__ __launch_bounds__(256) void k_self16(const float* __restrict__ feat,
                                                const float* __restrict__ dinv,
                                                float* __restrict__ outf, int total) {
    int t = blockIdx.x * 256 + threadIdx.x;
    if (t >= total) return;
    float dv = dinv[t >> 4];
    outf[t] = feat[t] * dv * dv;
}

__global__ __launch_bounds__(256) void k_out(const float* __restrict__ a,
                                             const float* __restrict__ W2,
                                             const float* __restrict__ b2,
                                             float* __restrict__ out, int n) {
    __shared__ float Ws[16 * 33];
    __shared__ float bs[32];
    for (int t = threadIdx.x; t < 512; t += 256) Ws[(t >> 5) * 33 + (t & 31)] = W2[t];
    if (threadIdx.x < 32) bs[threadIdx.x] = b2[threadIdx.x];
    __syncthreads();
    int t = blockIdx.x * 256 + threadIdx.x;
    int i = t >> 5, c = t & 31;
    if (i >= n) return;
    const float4* ar = reinterpret_cast<const float4*>(a + (size_t)i * 16);
    float acc = bs[c];
#pragma unroll
    for (int kk = 0; kk < 4; ++kk) {
        float4 v = ar[kk];
        acc += v.x * Ws[(4 * kk + 0) * 33 + c];
        acc += v.y * Ws[(4 * kk + 1) * 33 + c];
        acc += v.z * Ws[(4 * kk + 2) * 33 + c];
        acc += v.w * Ws[(4 * kk + 3) * 33 + c];
    }
    float m = acc;
#pragma unroll
    for (int o = 16; o > 0; o >>= 1) m = fmaxf(m, __shfl_xor(m, o, 32));
    float p = expf(acc - m);
#pragma unroll
    for (int o = 16; o > 0; o >>= 1) p += __shfl_xor(p, o, 32);
    out[t] = acc - m - logf(p);
}

extern "C" void kernel_launch(void* const* d_in, const int* in_sizes, int n_in,
                              void* d_out, int out_size, void* d_ws, size_t ws_size,
                              hipStream_t stream) {
    const float* x  = (const float*)d_in[0];
    const int* ei   = (const int*)d_in[1];
    const float* W1 = (const float*)d_in[2];
    const float* b1 = (const float*)d_in[3];
    const float* W2 = (const float*)d_in[4];
    const float* b2 = (const float*)d_in[5];
    float* out = (float*)d_out;

    const int n = in_sizes[0] / 512;
    const int E = in_sizes[1] / 2;
    const int* src = ei;
    const int* dst = ei + E;
    const int NB = (n + BK - 1) >> BKSH;
    const int gfill = (E + CHUNK - 1) / CHUNK;

    float* ws = (float*)d_ws;

    size_t u_dinv  = 0;
    size_t u_foffs = u_dinv + n;
    size_t u_nend  = u_foffs + n;
    size_t u_gcur  = u_nend + n;
    size_t u_gq    = u_gcur + NB;
    size_t u_gq2   = u_gq + (size_t)NB * SLAB;
    size_t u_h1    = u_gq2 + (size_t)NB * SLAB;
    size_t u_r1    = u_h1 + 16 * (size_t)n;
    size_t need    = (u_r1 + 16 * (size_t)n) * 4;

    if (ws_size >= need && NB <= MAXNB) {
        float* dinv = ws + u_dinv;
        int* offs   = (int*)(ws + u_foffs);
        int* nend   = (int*)(ws + u_nend);
        int* gcur   = (int*)(ws + u_gcur);
        int* gq     = (int*)(ws + u_gq);
        int* gq2    = (int*)(ws + u_gq2);
        unsigned short* gs1b = (unsigned short*)(ws + u_h1);
        unsigned short* r1sb = (unsigned short*)(ws + u_r1);

        k_init_cur<<<(NB + 255) / 256, 256, 0, stream>>>(gcur, NB);
        k_fill2   <<<gfill, 256, 0, stream>>>(src, dst, gcur, gq, E, NB);
        k_sortb   <<<NB, 256, 0, stream>>>(gq, gcur, gq2, offs, nend, dinv, n);
        k_gemm_mfma<<<512, 256, 0, stream>>>(x, W1, dinv, gs1b, n);
        k_agg_b   <<<(n * 16 + 255) / 256, 256, 0, stream>>>(gs1b, gq2, offs, nend,
                                                             dinv, b1, r1sb, n);
        k_agg_out <<<(n * 16 + 255) / 256, 256, 0, stream>>>(r1sb, gq2, offs, nend,
                                                             dinv, W2, b2, out, n);
    } else {
        float* dinv = ws;
        float* h1   = ws + n;
        float* r1   = ws + n + 16 * (size_t)n;
        int* cnt    = (int*)h1;
        float* agg2r = h1;

        const int total1 = E * 16;
        k_zero_i   <<<(n + 255) / 256, 256, 0, stream>>>(cnt, n);
        k_count    <<<(E + 255) / 256, 256, 0, stream>>>(dst, cnt, E);
        k_dinv     <<<(n + 255) / 256, 256, 0, stream>>>(cnt, dinv, n);
        k_gemm1    <<<1024, 256, 0, stream>>>(x, W1, dinv, h1, r1, n);
        k_scatter16<<<(total1 + 255) / 256, 256, 0, stream>>>(src, dst, h1, dinv, r1, total1);
        k_relu16   <<<(n * 16 + 255) / 256, 256, 0, stream>>>(r1, b1, n * 16);
        k_self16   <<<(n * 16 + 255) / 256, 256, 0, stream>>>(r1, dinv, agg2r, n * 16);
        k_scatter16<<<(total1 + 255) / 256, 256, 0, stream>>>(src, dst, r1, dinv, agg2r, total1);
        k_out      <<<(n * 32 + 255) / 256, 256, 0, stream>>>(agg2r, W2, b2, out, n);
    }
}

// Round 17
// 233.752 us; speedup vs baseline: 1.4629x; 1.0659x over previous
//
#include <hip/hip_runtime.h>
#include <hip/hip_bf16.h>

// GCN 2-layer forward, MI355X. F=512, H=16, C=32.
// r12 configuration (best measured: 240us) with one probe: fill2 CHUNK 6400.
// Slab binning (no prescan) -> per-bucket counting sort -> fine CSR ->
// 16-lane/8-unroll gather aggs over bf16 dinv-prescaled tables.
// gemm via direct MFMA (one 16-row tile per wave). Layer2 fused agg+W2+lsm.
// Norm factored: out[i] = dinv[i]*(gs[i] + sum_s gs[s]), gs = dinv.*feat.

#define BK 128
#define BKSH 7
#define MAXNB 1024
#define CHUNK 6400
#define SLAB 5120

typedef __attribute__((ext_vector_type(8))) short bf16x8;
typedef __attribute__((ext_vector_type(4))) float f32x4;

union ABpack { bf16x8 v; int i[4]; };

__device__ __forceinline__ int cvt2(float a, float b) {
    __hip_bfloat162 h = __float22bfloat162_rn(make_float2(a, b));
    return *reinterpret_cast<int*>(&h);
}
__device__ __forceinline__ unsigned short cvt1(float a) {
    __hip_bfloat16 h = __float2bfloat16(a);
    return *reinterpret_cast<unsigned short*>(&h);
}
__device__ __forceinline__ float b2f(unsigned short s) {
    return __uint_as_float(((unsigned)s) << 16);
}

__device__ __forceinline__ void load_lds16(const float* g, void* l) {
    __builtin_amdgcn_global_load_lds((const __attribute__((address_space(1))) void*)g,
                                     (__attribute__((address_space(3))) void*)l, 16, 0, 0);
}

__global__ __launch_bounds__(256) void k_init_cur(int* __restrict__ gcur, int NB) {
    int i = blockIdx.x * 256 + threadIdx.x;
    if (i < NB) gcur[i] = i * SLAB;
}

__global__ __launch_bounds__(256) void k_fill2(const int* __restrict__ src,
                                               const int* __restrict__ dst,
                                               int* __restrict__ gcur,
                                               int* __restrict__ gq, int E, int NB) {
    __shared__ int h[MAXNB];
    __shared__ int base[MAXNB];
    for (int t = threadIdx.x; t < NB; t += 256) h[t] = 0;
    __syncthreads();
    int e0 = blockIdx.x * CHUNK, e1 = min(E, e0 + CHUNK);
    for (int e = e0 + threadIdx.x; e < e1; e += 256)
        atomicAdd(&h[dst[e] >> BKSH], 1);
    __syncthreads();
    for (int t = threadIdx.x; t < NB; t += 256) {
        int c = h[t];
        base[t] = c ? atomicAdd(&gcur[t], c) : 0;
    }
    __syncthreads();
    for (int t = threadIdx.x; t < NB; t += 256) h[t] = 0;
    __syncthreads();
    for (int e = e0 + threadIdx.x; e < e1; e += 256) {
        int d = dst[e], b = d >> BKSH;
        int loc = atomicAdd(&h[b], 1);
        gq[base[b] + loc] = (src[e] << BKSH) | (d & (BK - 1));
    }
}

__global__ __launch_bounds__(256) void k_sortb(const int* __restrict__ gq,
                                               const int* __restrict__ gcur,
                                               int* __restrict__ gq2,
                                               int* __restrict__ offs,
                                               int* __restrict__ nend,
                                               float* __restrict__ dinv, int n) {
    __shared__ int cnt[BK];
    __shared__ int cur[BK];
    int b = blockIdx.x;
    int p0 = b * SLAB, p1 = gcur[b];
    if (threadIdx.x < BK) cnt[threadIdx.x] = 0;
    __syncthreads();
    for (int p = p0 + threadIdx.x; p < p1; p += 256)
        atomicAdd(&cnt[__builtin_nontemporal_load(gq + p) & (BK - 1)], 1);
    __syncthreads();
    if (threadIdx.x < BK) cur[threadIdx.x] = cnt[threadIdx.x];
    __syncthreads();
    for (int o = 1; o < BK; o <<= 1) {
        int v = (threadIdx.x < BK && threadIdx.x >= o) ? cur[threadIdx.x - o] : 0;
        __syncthreads();
        if (threadIdx.x < BK) cur[threadIdx.x] += v;
        __syncthreads();
    }
    if (threadIdx.x < BK) {
        int c = cnt[threadIdx.x];
        int excl = cur[threadIdx.x] - c;
        int node = (b << BKSH) + threadIdx.x;
        if (node < n) {
            offs[node] = p0 + excl;
            nend[node] = p0 + excl + c;
            dinv[node] = rsqrtf((float)(c + 1));
        }
        cur[threadIdx.x] = excl;
    }
    __syncthreads();
    for (int p = p0 + threadIdx.x; p < p1; p += 256) {
        int e = __builtin_nontemporal_load(gq + p);
        int loc = atomicAdd(&cur[e & (BK - 1)], 1);
        gq2[p0 + loc] = e >> BKSH;
    }
}

__global__ __launch_bounds__(256) void k_gemm_mfma(const float* __restrict__ x,
                                                   const float* __restrict__ W1,
                                                   const float* __restrict__ dinv,
                                                   unsigned short* __restrict__ gs1,
                                                   int n) {
    const int lane = threadIdx.x & 63;
    const int r = lane & 15;
    const int g4 = lane >> 4;
    const int wid = blockIdx.x * 4 + (threadIdx.x >> 6);
    const int nw = gridDim.x * 4;

    ABpack wf[16];
#pragma unroll
    for (int s = 0; s < 16; ++s) {
        int kb = s * 32 + g4 * 8;
#pragma unroll
        for (int j = 0; j < 4; ++j)
            wf[s].i[j] = cvt2(W1[(size_t)(kb + 2 * j) * 16 + r],
                              W1[(size_t)(kb + 2 * j + 1) * 16 + r]);
    }

    const int ntiles = (n + 15) >> 4;
    for (int tile = wid; tile < ntiles; tile += nw) {
        int m0 = tile << 4;
        int arow = m0 + r;
        if (arow >= n) arow = n - 1;
        const float* xp = x + (size_t)arow * 512 + g4 * 8;
        f32x4 acc = {0.f, 0.f, 0.f, 0.f};
#pragma unroll
        for (int s = 0; s < 16; ++s) {
            f32x4 f0 = __builtin_nontemporal_load(reinterpret_cast<const f32x4*>(xp + s * 32));
            f32x4 f1 = __builtin_nontemporal_load(reinterpret_cast<const f32x4*>(xp + s * 32 + 4));
            ABpack ah;
            ah.i[0] = cvt2(f0[0], f0[1]);
            ah.i[1] = cvt2(f0[2], f0[3]);
            ah.i[2] = cvt2(f1[0], f1[1]);
            ah.i[3] = cvt2(f1[2], f1[3]);
            acc = __builtin_amdgcn_mfma_f32_16x16x32_bf16(ah.v, wf[s].v, acc, 0, 0, 0);
        }
#pragma unroll
        for (int j = 0; j < 4; ++j) {
            int crow = m0 + g4 * 4 + j;
            if (crow < n) {
                float dvv = dinv[crow];
                gs1[(size_t)crow * 16 + r] = cvt1(acc[j] * dvv);
            }
        }
    }
}

__global__ __launch_bounds__(256) void k_agg_b(const unsigned short* __restrict__ featb,
                                               const int* __restrict__ gq2,
                                               const int* __restrict__ offs,
                                               const int* __restrict__ nend,
                                               const float* __restrict__ dinv,
                                               const float* __restrict__ bias,
                                               unsigned short* __restrict__ out_b,
                                               int n) {
    int t = blockIdx.x * 256 + threadIdx.x;
    int i = t >> 4, k = t & 15;
    if (i >= n) return;
    float acc = b2f(featb[(size_t)i * 16 + k]);
    int p = offs[i], p1 = nend[i];
    for (; p + 8 <= p1; p += 8) {
        int s0 = __builtin_nontemporal_load(gq2 + p);
        int s1 = __builtin_nontemporal_load(gq2 + p + 1);
        int s2 = __builtin_nontemporal_load(gq2 + p + 2);
        int s3 = __builtin_nontemporal_load(gq2 + p + 3);
        int s4 = __builtin_nontemporal_load(gq2 + p + 4);
        int s5 = __builtin_nontemporal_load(gq2 + p + 5);
        int s6 = __builtin_nontemporal_load(gq2 + p + 6);
        int s7 = __builtin_nontemporal_load(gq2 + p + 7);
        float v0 = b2f(featb[(size_t)s0 * 16 + k]);
        float v1 = b2f(featb[(size_t)s1 * 16 + k]);
        float v2 = b2f(featb[(size_t)s2 * 16 + k]);
        float v3 = b2f(featb[(size_t)s3 * 16 + k]);
        float v4 = b2f(featb[(size_t)s4 * 16 + k]);
        float v5 = b2f(featb[(size_t)s5 * 16 + k]);
        float v6 = b2f(featb[(size_t)s6 * 16 + k]);
        float v7 = b2f(featb[(size_t)s7 * 16 + k]);
        acc += ((v0 + v1) + (v2 + v3)) + ((v4 + v5) + (v6 + v7));
    }
    for (; p < p1; ++p)
        acc += b2f(featb[(size_t)__builtin_nontemporal_load(gq2 + p) * 16 + k]);
    float dvi = dinv[i];
    float v = fmaxf(dvi * acc + bias[k], 0.f) * dvi;
    out_b[(size_t)i * 16 + k] = cvt1(v);
}

__global__ __launch_bounds__(256) void k_agg_out(const unsigned short* __restrict__ featb,
                                                 const int* __restrict__ gq2,
                                                 const int* __restrict__ offs,
                                                 const int* __restrict__ nend,
                                                 const float* __restrict__ dinv,
                                                 const float* __restrict__ W2,
                                                 const float* __restrict__ b2,
                                                 float* __restrict__ out, int n) {
    __shared__ float Ws[16 * 33];
    __shared__ float bs[32];
    __shared__ float As[16][17];
    for (int t = threadIdx.x; t < 512; t += 256) Ws[(t >> 5) * 33 + (t & 31)] = W2[t];
    if (threadIdx.x < 32) bs[threadIdx.x] = b2[threadIdx.x];

    int t = blockIdx.x * 256 + threadIdx.x;
    int i = t >> 4, k = t & 15, nl = threadIdx.x >> 4;
    float acc = 0.f;
    if (i < n) {
        acc = b2f(featb[(size_t)i * 16 + k]);
        int p = offs[i], p1 = nend[i];
        for (; p + 8 <= p1; p += 8) {
            int s0 = __builtin_nontemporal_load(gq2 + p);
            int s1 = __builtin_nontemporal_load(gq2 + p + 1);
            int s2 = __builtin_nontemporal_load(gq2 + p + 2);
            int s3 = __builtin_nontemporal_load(gq2 + p + 3);
            int s4 = __builtin_nontemporal_load(gq2 + p + 4);
            int s5 = __builtin_nontemporal_load(gq2 + p + 5);
            int s6 = __builtin_nontemporal_load(gq2 + p + 6);
            int s7 = __builtin_nontemporal_load(gq2 + p + 7);
            float v0 = b2f(featb[(size_t)s0 * 16 + k]);
            float v1 = b2f(featb[(size_t)s1 * 16 + k]);
            float v2 = b2f(featb[(size_t)s2 * 16 + k]);
            float v3 = b2f(featb[(size_t)s3 * 16 + k]);
            float v4 = b2f(featb[(size_t)s4 * 16 + k]);
            float v5 = b2f(featb[(size_t)s5 * 16 + k]);
            float v6 = b2f(featb[(size_t)s6 * 16 + k]);
            float v7 = b2f(featb[(size_t)s7 * 16 + k]);
            acc += ((v0 + v1) + (v2 + v3)) + ((v4 + v5) + (v6 + v7));
        }
        for (; p < p1; ++p)
            acc += b2f(featb[(size_t)__builtin_nontemporal_load(gq2 + p) * 16 + k]);
        acc *= dinv[i];
    }
    As[nl][k] = acc;
    __syncthreads();
    if (i < n) {
        float v0 = bs[k], v1 = bs[k + 16];
#pragma unroll
        for (int kk = 0; kk < 16; ++kk) {
            float a = As[nl][kk];
            v0 += a * Ws[kk * 33 + k];
            v1 += a * Ws[kk * 33 + k + 16];
        }
        float m = fmaxf(v0, v1);
#pragma unroll
        for (int o = 8; o > 0; o >>= 1) m = fmaxf(m, __shfl_xor(m, o, 16));
        float pp = expf(v0 - m) + expf(v1 - m);
#pragma unroll
        for (int o = 8; o > 0; o >>= 1) pp += __shfl_xor(pp, o, 16);
        float lg = logf(pp);
        float* op = out + (size_t)i * 32;
        op[k] = v0 - m - lg;
        op[k + 16] = v1 - m - lg;
    }
}

// ---- fallback path kernels (atomic scatter, fp32) ----
__global__ __launch_bounds__(256) void k_zero_i(int* __restrict__ p, int n) {
    int i = blockIdx.x * 256 + threadIdx.x;
    if (i < n) p[i] = 0;
}

__global__ __launch_bounds__(256) void k_count(const int* __restrict__ dst,
                                               int* __restrict__ cnt, int E) {
    int e = blockIdx.x * 256 + threadIdx.x;
    if (e < E) atomicAdd(&cnt[dst[e]], 1);
}

__global__ __launch_bounds__(256) void k_dinv(const int* __restrict__ cnt,
                                              float* __restrict__ dinv, int n) {
    int i = blockIdx.x * 256 + threadIdx.x;
    if (i < n) dinv[i] = rsqrtf((float)(cnt[i] + 1));
}

__global__ __launch_bounds__(256) void k_gemm1(const float* __restrict__ x,
                                               const float* __restrict__ W1,
                                               const float* __restrict__ dinv,
                                               float* __restrict__ h1,
                                               float* __restrict__ r1self, int n) {
    __shared__ float Ws[8192];
    __shared__ float4 Xs[4][512];
    for (int t = threadIdx.x; t < 8192; t += 256) {
        int sa = t ^ (((t >> 9) & 1) << 4);
        Ws[sa] = W1[t];
    }
    __syncthreads();
    const int wave = threadIdx.x >> 6;
    const int lane = threadIdx.x & 63;
    const int q = lane & 15, g = lane >> 4;
    const int sr = lane >> 3, su = lane & 7;
    const int first = blockIdx.x * 4 + wave;
    const int stride = gridDim.x * 4;
    const int ngroups = (n + 7) >> 3;
    if (first >= ngroups) return;
    const int mygroups = (ngroups - first + stride - 1) / stride;
    const int T = mygroups * 4;
    char* xbase = (char*)(&Xs[wave][0]);
    auto stage = [&](int i) {
        int k = i >> 2, c = i & 3;
        int r0 = (first + k * stride) << 3;
        int row = r0 + sr;
        if (row >= n) row = n - 1;
        const float* gp = x + (size_t)row * 512 + c * 128 + su * 4;
        char* lb = xbase + (i & 1) * 4096;
#pragma unroll
        for (int m = 0; m < 4; ++m) load_lds16(gp + m * 32, lb + m * 1024);
    };
    stage(0);
    if (T > 1) stage(1);
    int issued = (T > 1) ? 2 : 1;
    float acc[8];
    const float4* xw = &Xs[wave][0];
    const int flip = (g & 1) << 4;
    for (int i = 0; i < T; ++i) {
        if (i < T - 1) asm volatile("s_waitcnt vmcnt(4)" ::: "memory");
        else           asm volatile("s_waitcnt vmcnt(0)" ::: "memory");
        int c = i & 3;
        const float4* xb = xw + (i & 1) * 256;
        if (c == 0) {
#pragma unroll
            for (int r = 0; r < 8; ++r) acc[r] = 0.f;
        }
        const int aW = 2048 * c + 512 * g + q;
#pragma unroll
        for (int t = 0; t < 8; ++t) {
            int tg = (t + g) & 7;
            float4 xv[8];
#pragma unroll
            for (int r = 0; r < 8; ++r) xv[r] = xb[g * 64 + r * 8 + tg];
            int a0 = aW + 64 * tg;
            float w0 = Ws[(a0) ^ flip];
            float w1 = Ws[(a0 + 16) ^ flip];
            float w2 = Ws[(a0 + 32) ^ flip];
            float w3 = Ws[(a0 + 48) ^ flip];
#pragma unroll
            for (int r = 0; r < 8; ++r)
                acc[r] += xv[r].x * w0 + xv[r].y * w1 + xv[r].z * w2 + xv[r].w * w3;
        }
        if (issued < T) { stage(issued); ++issued; }
        if (c == 3) {
            int r0 = (first + (i >> 2) * stride) << 3;
#pragma unroll
            for (int r = 0; r < 8; ++r) {
                acc[r] += __shfl_xor(acc[r], 16);
                acc[r] += __shfl_xor(acc[r], 32);
            }
            float v0 = 0.f, v1 = 0.f;
#pragma unroll
            for (int r = 0; r < 4; ++r)
                if (g == r) { v0 = acc[r]; v1 = acc[r + 4]; }
            int row0 = r0 + g, row1 = r0 + 4 + g;
            if (row0 < n) {
                h1[(size_t)row0 * 16 + q] = v0;
                if (r1self) { float dv = dinv[row0]; r1self[(size_t)row0 * 16 + q] = v0 * dv * dv; }
            }
            if (row1 < n) {
                h1[(size_t)row1 * 16 + q] = v1;
                if (r1self) { float dv = dinv[row1]; r1self[(size_t)row1 * 16 + q] = v1 * dv * dv; }
            }
        }
    }
}

__global__ __launch_bounds__(256) void k_scatter16(const int* __restrict__ src,
                                                   const int* __restrict__ dst,
                                                   const float* __restrict__ feat,
                                                   const float* __restrict__ dinv,
                                                   float* __restrict__ outf, int total) {
    int t = blockIdx.x * 256 + threadIdx.x;
    if (t >= total) return;
    int e = t >> 4, k = t & 15;
    int s = src[e], d = dst[e];
    float w = dinv[s] * dinv[d];
    unsafeAtomicAdd(&outf[(size_t)d * 16 + k], feat[(size_t)s * 16 + k] * w);
}

__global__ __launch_bounds__(256) void k_relu16(float* __restrict__ r1,
                                                const float* __restrict__ b1, int total) {
    int t = blockIdx.x * 256 + threadIdx.x;
    if (t < total) r1[t] = fmaxf(r1[t] + b1[t & 15], 0.f);
}

__global__ __launch_bounds__(256) void k_self16(const float* __restrict__ feat,
                                                const float* __restrict__ dinv,
                                                float* __restrict__ outf, int total) {
    int t = blockIdx.x * 256 + threadIdx.x;
    if (t >= total) return;
    float dv = dinv[t >> 4];
    outf[t] = feat[t] * dv * dv;
}

__global__ __launch_bounds__(256) void k_out(const float* __restrict__ a,
                                             const float* __restrict__ W2,
                                             const float* __restrict__ b2,
                                             float* __restrict__ out, int n) {
    __shared__ float Ws[16 * 33];
    __shared__ float bs[32];
    for (int t = threadIdx.x; t < 512; t += 256) Ws[(t >> 5) * 33 + (t & 31)] = W2[t];
    if (threadIdx.x < 32) bs[threadIdx.x] = b2[threadIdx.x];
    __syncthreads();
    int t = blockIdx.x * 256 + threadIdx.x;
    int i = t >> 5, c = t & 31;
    if (i >= n) return;
    const float4* ar = reinterpret_cast<const float4*>(a + (size_t)i * 16);
    float acc = bs[c];
#pragma unroll
    for (int kk = 0; kk < 4; ++kk) {
        float4 v = ar[kk];
        acc += v.x * Ws[(4 * kk + 0) * 33 + c];
        acc += v.y * Ws[(4 * kk + 1) * 33 + c];
        acc += v.z * Ws[(4 * kk + 2) * 33 + c];
        acc += v.w * Ws[(4 * kk + 3) * 33 + c];
    }
    float m = acc;
#pragma unroll
    for (int o = 16; o > 0; o >>= 1) m = fmaxf(m, __shfl_xor(m, o, 32));
    float p = expf(acc - m);
#pragma unroll
    for (int o = 16; o > 0; o >>= 1) p += __shfl_xor(p, o, 32);
    out[t] = acc - m - logf(p);
}

extern "C" void kernel_launch(void* const* d_in, const int* in_sizes, int n_in,
                              void* d_out, int out_size, void* d_ws, size_t ws_size,
                              hipStream_t stream) {
    const float* x  = (const float*)d_in[0];
    const int* ei   = (const int*)d_in[1];
    const float* W1 = (const float*)d_in[2];
    const float* b1 = (const float*)d_in[3];
    const float* W2 = (const float*)d_in[4];
    const float* b2 = (const float*)d_in[5];
    float* out = (float*)d_out;

    const int n = in_sizes[0] / 512;
    const int E = in_sizes[1] / 2;
    const int* src = ei;
    const int* dst = ei + E;
    const int NB = (n + BK - 1) >> BKSH;
    const int gfill = (E + CHUNK - 1) / CHUNK;
    const int ntiles = (n + 15) >> 4;
    const int ggemm = (ntiles + 3) / 4;

    float* ws = (float*)d_ws;

    size_t u_dinv  = 0;
    size_t u_foffs = u_dinv + n;
    size_t u_nend  = u_foffs + n;
    size_t u_gcur  = u_nend + n;
    size_t u_gq    = u_gcur + NB;
    size_t u_gq2   = u_gq + (size_t)NB * SLAB;
    size_t u_h1    = u_gq2 + (size_t)NB * SLAB;
    size_t u_r1    = u_h1 + 16 * (size_t)n;
    size_t need    = (u_r1 + 16 * (size_t)n) * 4;

    if (ws_size >= need && NB <= MAXNB) {
        float* dinv = ws + u_dinv;
        int* offs   = (int*)(ws + u_foffs);
        int* nend   = (int*)(ws + u_nend);
        int* gcur   = (int*)(ws + u_gcur);
        int* gq     = (int*)(ws + u_gq);
        int* gq2    = (int*)(ws + u_gq2);
        unsigned short* gs1b = (unsigned short*)(ws + u_h1);
        unsigned short* r1sb = (unsigned short*)(ws + u_r1);

        k_init_cur<<<(NB + 255) / 256, 256, 0, stream>>>(gcur, NB);
        k_fill2   <<<gfill, 256, 0, stream>>>(src, dst, gcur, gq, E, NB);
        k_sortb   <<<NB, 256, 0, stream>>>(gq, gcur, gq2, offs, nend, dinv, n);
        k_gemm_mfma<<<ggemm, 256, 0, stream>>>(x, W1, dinv, gs1b, n);
        k_agg_b   <<<(n * 16 + 255) / 256, 256, 0, stream>>>(gs1b, gq2, offs, nend,
                                                             dinv, b1, r1sb, n);
        k_agg_out <<<(n * 16 + 255) / 256, 256, 0, stream>>>(r1sb, gq2, offs, nend,
                                                             dinv, W2, b2, out, n);
    } else {
        float* dinv = ws;
        float* h1   = ws + n;
        float* r1   = ws + n + 16 * (size_t)n;
        int* cnt    = (int*)h1;
        float* agg2r = h1;

        const int total1 = E * 16;
        k_zero_i   <<<(n + 255) / 256, 256, 0, stream>>>(cnt, n);
        k_count    <<<(E + 255) / 256, 256, 0, stream>>>(dst, cnt, E);
        k_dinv     <<<(n + 255) / 256, 256, 0, stream>>>(cnt, dinv, n);
        k_gemm1    <<<1024, 256, 0, stream>>>(x, W1, dinv, h1, r1, n);
        k_scatter16<<<(total1 + 255) / 256, 256, 0, stream>>>(src, dst, h1, dinv, r1, total1);
        k_relu16   <<<(n * 16 + 255) / 256, 256, 0, stream>>>(r1, b1, n * 16);
        k_self16   <<<(n * 16 + 255) / 256, 256, 0, stream>>>(r1, dinv, agg2r, n * 16);
        k_scatter16<<<(total1 + 255) / 256, 256, 0, stream>>>(src, dst, r1, dinv, agg2r, total1);
        k_out      <<<(n * 32 + 255) / 256, 256, 0, stream>>>(agg2r, W2, b2, out, n);
    }
}

// Round 18
// 230.584 us; speedup vs baseline: 1.4830x; 1.0137x over previous
//
#include <hip/hip_runtime.h>
#include <hip/hip_bf16.h>

// GCN 2-layer forward, MI355X. F=512, H=16, C=32.
// r17 configuration (best measured: 233.75us) with one probe: k_sortb caches
// its slab in LDS (single global read; scatter from LDS).
// Slab binning (no prescan) -> per-bucket counting sort -> fine CSR ->
// 16-lane/8-unroll gather aggs over bf16 dinv-prescaled tables.
// gemm via direct MFMA (one 16-row tile per wave). Layer2 fused agg+W2+lsm.
// Norm factored: out[i] = dinv[i]*(gs[i] + sum_s gs[s]), gs = dinv.*feat.

#define BK 128
#define BKSH 7
#define MAXNB 1024
#define CHUNK 6400
#define SLAB 5120

typedef __attribute__((ext_vector_type(8))) short bf16x8;
typedef __attribute__((ext_vector_type(4))) float f32x4;

union ABpack { bf16x8 v; int i[4]; };

__device__ __forceinline__ int cvt2(float a, float b) {
    __hip_bfloat162 h = __float22bfloat162_rn(make_float2(a, b));
    return *reinterpret_cast<int*>(&h);
}
__device__ __forceinline__ unsigned short cvt1(float a) {
    __hip_bfloat16 h = __float2bfloat16(a);
    return *reinterpret_cast<unsigned short*>(&h);
}
__device__ __forceinline__ float b2f(unsigned short s) {
    return __uint_as_float(((unsigned)s) << 16);
}

__device__ __forceinline__ void load_lds16(const float* g, void* l) {
    __builtin_amdgcn_global_load_lds((const __attribute__((address_space(1))) void*)g,
                                     (__attribute__((address_space(3))) void*)l, 16, 0, 0);
}

__global__ __launch_bounds__(256) void k_init_cur(int* __restrict__ gcur, int NB) {
    int i = blockIdx.x * 256 + threadIdx.x;
    if (i < NB) gcur[i] = i * SLAB;
}

__global__ __launch_bounds__(256) void k_fill2(const int* __restrict__ src,
                                               const int* __restrict__ dst,
                                               int* __restrict__ gcur,
                                               int* __restrict__ gq, int E, int NB) {
    __shared__ int h[MAXNB];
    __shared__ int base[MAXNB];
    for (int t = threadIdx.x; t < NB; t += 256) h[t] = 0;
    __syncthreads();
    int e0 = blockIdx.x * CHUNK, e1 = min(E, e0 + CHUNK);
    for (int e = e0 + threadIdx.x; e < e1; e += 256)
        atomicAdd(&h[dst[e] >> BKSH], 1);
    __syncthreads();
    for (int t = threadIdx.x; t < NB; t += 256) {
        int c = h[t];
        base[t] = c ? atomicAdd(&gcur[t], c) : 0;
    }
    __syncthreads();
    for (int t = threadIdx.x; t < NB; t += 256) h[t] = 0;
    __syncthreads();
    for (int e = e0 + threadIdx.x; e < e1; e += 256) {
        int d = dst[e], b = d >> BKSH;
        int loc = atomicAdd(&h[b], 1);
        gq[base[b] + loc] = (src[e] << BKSH) | (d & (BK - 1));
    }
}

// Per-bucket counting sort; slab cached in LDS (single global read).
__global__ __launch_bounds__(256) void k_sortb(const int* __restrict__ gq,
                                               const int* __restrict__ gcur,
                                               int* __restrict__ gq2,
                                               int* __restrict__ offs,
                                               int* __restrict__ nend,
                                               float* __restrict__ dinv, int n) {
    __shared__ int slab[SLAB];
    __shared__ int cnt[BK];
    __shared__ int cur[BK];
    int b = blockIdx.x;
    int p0 = b * SLAB;
    int len = gcur[b] - p0;
    if (threadIdx.x < BK) cnt[threadIdx.x] = 0;
    __syncthreads();
    for (int p = threadIdx.x; p < len; p += 256) {
        int e = __builtin_nontemporal_load(gq + p0 + p);
        slab[p] = e;
        atomicAdd(&cnt[e & (BK - 1)], 1);
    }
    __syncthreads();
    if (threadIdx.x < BK) cur[threadIdx.x] = cnt[threadIdx.x];
    __syncthreads();
    for (int o = 1; o < BK; o <<= 1) {
        int v = (threadIdx.x < BK && threadIdx.x >= o) ? cur[threadIdx.x - o] : 0;
        __syncthreads();
        if (threadIdx.x < BK) cur[threadIdx.x] += v;
        __syncthreads();
    }
    if (threadIdx.x < BK) {
        int c = cnt[threadIdx.x];
        int excl = cur[threadIdx.x] - c;
        int node = (b << BKSH) + threadIdx.x;
        if (node < n) {
            offs[node] = p0 + excl;
            nend[node] = p0 + excl + c;
            dinv[node] = rsqrtf((float)(c + 1));
        }
        cur[threadIdx.x] = excl;
    }
    __syncthreads();
    for (int p = threadIdx.x; p < len; p += 256) {
        int e = slab[p];
        int loc = atomicAdd(&cur[e & (BK - 1)], 1);
        gq2[p0 + loc] = e >> BKSH;
    }
}

__global__ __launch_bounds__(256) void k_gemm_mfma(const float* __restrict__ x,
                                                   const float* __restrict__ W1,
                                                   const float* __restrict__ dinv,
                                                   unsigned short* __restrict__ gs1,
                                                   int n) {
    const int lane = threadIdx.x & 63;
    const int r = lane & 15;
    const int g4 = lane >> 4;
    const int wid = blockIdx.x * 4 + (threadIdx.x >> 6);
    const int nw = gridDim.x * 4;

    ABpack wf[16];
#pragma unroll
    for (int s = 0; s < 16; ++s) {
        int kb = s * 32 + g4 * 8;
#pragma unroll
        for (int j = 0; j < 4; ++j)
            wf[s].i[j] = cvt2(W1[(size_t)(kb + 2 * j) * 16 + r],
                              W1[(size_t)(kb + 2 * j + 1) * 16 + r]);
    }

    const int ntiles = (n + 15) >> 4;
    for (int tile = wid; tile < ntiles; tile += nw) {
        int m0 = tile << 4;
        int arow = m0 + r;
        if (arow >= n) arow = n - 1;
        const float* xp = x + (size_t)arow * 512 + g4 * 8;
        f32x4 acc = {0.f, 0.f, 0.f, 0.f};
#pragma unroll
        for (int s = 0; s < 16; ++s) {
            f32x4 f0 = __builtin_nontemporal_load(reinterpret_cast<const f32x4*>(xp + s * 32));
            f32x4 f1 = __builtin_nontemporal_load(reinterpret_cast<const f32x4*>(xp + s * 32 + 4));
            ABpack ah;
            ah.i[0] = cvt2(f0[0], f0[1]);
            ah.i[1] = cvt2(f0[2], f0[3]);
            ah.i[2] = cvt2(f1[0], f1[1]);
            ah.i[3] = cvt2(f1[2], f1[3]);
            acc = __builtin_amdgcn_mfma_f32_16x16x32_bf16(ah.v, wf[s].v, acc, 0, 0, 0);
        }
#pragma unroll
        for (int j = 0; j < 4; ++j) {
            int crow = m0 + g4 * 4 + j;
            if (crow < n) {
                float dvv = dinv[crow];
                gs1[(size_t)crow * 16 + r] = cvt1(acc[j] * dvv);
            }
        }
    }
}

__global__ __launch_bounds__(256) void k_agg_b(const unsigned short* __restrict__ featb,
                                               const int* __restrict__ gq2,
                                               const int* __restrict__ offs,
                                               const int* __restrict__ nend,
                                               const float* __restrict__ dinv,
                                               const float* __restrict__ bias,
                                               unsigned short* __restrict__ out_b,
                                               int n) {
    int t = blockIdx.x * 256 + threadIdx.x;
    int i = t >> 4, k = t & 15;
    if (i >= n) return;
    float acc = b2f(featb[(size_t)i * 16 + k]);
    int p = offs[i], p1 = nend[i];
    for (; p + 8 <= p1; p += 8) {
        int s0 = __builtin_nontemporal_load(gq2 + p);
        int s1 = __builtin_nontemporal_load(gq2 + p + 1);
        int s2 = __builtin_nontemporal_load(gq2 + p + 2);
        int s3 = __builtin_nontemporal_load(gq2 + p + 3);
        int s4 = __builtin_nontemporal_load(gq2 + p + 4);
        int s5 = __builtin_nontemporal_load(gq2 + p + 5);
        int s6 = __builtin_nontemporal_load(gq2 + p + 6);
        int s7 = __builtin_nontemporal_load(gq2 + p + 7);
        float v0 = b2f(featb[(size_t)s0 * 16 + k]);
        float v1 = b2f(featb[(size_t)s1 * 16 + k]);
        float v2 = b2f(featb[(size_t)s2 * 16 + k]);
        float v3 = b2f(featb[(size_t)s3 * 16 + k]);
        float v4 = b2f(featb[(size_t)s4 * 16 + k]);
        float v5 = b2f(featb[(size_t)s5 * 16 + k]);
        float v6 = b2f(featb[(size_t)s6 * 16 + k]);
        float v7 = b2f(featb[(size_t)s7 * 16 + k]);
        acc += ((v0 + v1) + (v2 + v3)) + ((v4 + v5) + (v6 + v7));
    }
    for (; p < p1; ++p)
        acc += b2f(featb[(size_t)__builtin_nontemporal_load(gq2 + p) * 16 + k]);
    float dvi = dinv[i];
    float v = fmaxf(dvi * acc + bias[k], 0.f) * dvi;
    out_b[(size_t)i * 16 + k] = cvt1(v);
}

__global__ __launch_bounds__(256) void k_agg_out(const unsigned short* __restrict__ featb,
                                                 const int* __restrict__ gq2,
                                                 const int* __restrict__ offs,
                                                 const int* __restrict__ nend,
                                                 const float* __restrict__ dinv,
                                                 const float* __restrict__ W2,
                                                 const float* __restrict__ b2,
                                                 float* __restrict__ out, int n) {
    __shared__ float Ws[16 * 33];
    __shared__ float bs[32];
    __shared__ float As[16][17];
    for (int t = threadIdx.x; t < 512; t += 256) Ws[(t >> 5) * 33 + (t & 31)] = W2[t];
    if (threadIdx.x < 32) bs[threadIdx.x] = b2[threadIdx.x];

    int t = blockIdx.x * 256 + threadIdx.x;
    int i = t >> 4, k = t & 15, nl = threadIdx.x >> 4;
    float acc = 0.f;
    if (i < n) {
        acc = b2f(featb[(size_t)i * 16 + k]);
        int p = offs[i], p1 = nend[i];
        for (; p + 8 <= p1; p += 8) {
            int s0 = __builtin_nontemporal_load(gq2 + p);
            int s1 = __builtin_nontemporal_load(gq2 + p + 1);
            int s2 = __builtin_nontemporal_load(gq2 + p + 2);
            int s3 = __builtin_nontemporal_load(gq2 + p + 3);
            int s4 = __builtin_nontemporal_load(gq2 + p + 4);
            int s5 = __builtin_nontemporal_load(gq2 + p + 5);
            int s6 = __builtin_nontemporal_load(gq2 + p + 6);
            int s7 = __builtin_nontemporal_load(gq2 + p + 7);
            float v0 = b2f(featb[(size_t)s0 * 16 + k]);
            float v1 = b2f(featb[(size_t)s1 * 16 + k]);
            float v2 = b2f(featb[(size_t)s2 * 16 + k]);
            float v3 = b2f(featb[(size_t)s3 * 16 + k]);
            float v4 = b2f(featb[(size_t)s4 * 16 + k]);
            float v5 = b2f(featb[(size_t)s5 * 16 + k]);
            float v6 = b2f(featb[(size_t)s6 * 16 + k]);
            float v7 = b2f(featb[(size_t)s7 * 16 + k]);
            acc += ((v0 + v1) + (v2 + v3)) + ((v4 + v5) + (v6 + v7));
        }
        for (; p < p1; ++p)
            acc += b2f(featb[(size_t)__builtin_nontemporal_load(gq2 + p) * 16 + k]);
        acc *= dinv[i];
    }
    As[nl][k] = acc;
    __syncthreads();
    if (i < n) {
        float v0 = bs[k], v1 = bs[k + 16];
#pragma unroll
        for (int kk = 0; kk < 16; ++kk) {
            float a = As[nl][kk];
            v0 += a * Ws[kk * 33 + k];
            v1 += a * Ws[kk * 33 + k + 16];
        }
        float m = fmaxf(v0, v1);
#pragma unroll
        for (int o = 8; o > 0; o >>= 1) m = fmaxf(m, __shfl_xor(m, o, 16));
        float pp = expf(v0 - m) + expf(v1 - m);
#pragma unroll
        for (int o = 8; o > 0; o >>= 1) pp += __shfl_xor(pp, o, 16);
        float lg = logf(pp);
        float* op = out + (size_t)i * 32;
        op[k] = v0 - m - lg;
        op[k + 16] = v1 - m - lg;
    }
}

// ---- fallback path kernels (atomic scatter, fp32) ----
__global__ __launch_bounds__(256) void k_zero_i(int* __restrict__ p, int n) {
    int i = blockIdx.x * 256 + threadIdx.x;
    if (i < n) p[i] = 0;
}

__global__ __launch_bounds__(256) void k_count(const int* __restrict__ dst,
                                               int* __restrict__ cnt, int E) {
    int e = blockIdx.x * 256 + threadIdx.x;
    if (e < E) atomicAdd(&cnt[dst[e]], 1);
}

__global__ __launch_bounds__(256) void k_dinv(const int* __restrict__ cnt,
                                              float* __restrict__ dinv, int n) {
    int i = blockIdx.x * 256 + threadIdx.x;
    if (i < n) dinv[i] = rsqrtf((float)(cnt[i] + 1));
}

__global__ __launch_bounds__(256) void k_gemm1(const float* __restrict__ x,
                                               const float* __restrict__ W1,
                                               const float* __restrict__ dinv,
                                               float* __restrict__ h1,
                                               float* __restrict__ r1self, int n) {
    __shared__ float Ws[8192];
    __shared__ float4 Xs[4][512];
    for (int t = threadIdx.x; t < 8192; t += 256) {
        int sa = t ^ (((t >> 9) & 1) << 4);
        Ws[sa] = W1[t];
    }
    __syncthreads();
    const int wave = threadIdx.x >> 6;
    const int lane = threadIdx.x & 63;
    const int q = lane & 15, g = lane >> 4;
    const int sr = lane >> 3, su = lane & 7;
    const int first = blockIdx.x * 4 + wave;
    const int stride = gridDim.x * 4;
    const int ngroups = (n + 7) >> 3;
    if (first >= ngroups) return;
    const int mygroups = (ngroups - first + stride - 1) / stride;
    const int T = mygroups * 4;
    char* xbase = (char*)(&Xs[wave][0]);
    auto stage = [&](int i) {
        int k = i >> 2, c = i & 3;
        int r0 = (first + k * stride) << 3;
        int row = r0 + sr;
        if (row >= n) row = n - 1;
        const float* gp = x + (size_t)row * 512 + c * 128 + su * 4;
        char* lb = xbase + (i & 1) * 4096;
#pragma unroll
        for (int m = 0; m < 4; ++m) load_lds16(gp + m * 32, lb + m * 1024);
    };
    stage(0);
    if (T > 1) stage(1);
    int issued = (T > 1) ? 2 : 1;
    float acc[8];
    const float4* xw = &Xs[wave][0];
    const int flip = (g & 1) << 4;
    for (int i = 0; i < T; ++i) {
        if (i < T - 1) asm volatile("s_waitcnt vmcnt(4)" ::: "memory");
        else           asm volatile("s_waitcnt vmcnt(0)" ::: "memory");
        int c = i & 3;
        const float4* xb = xw + (i & 1) * 256;
        if (c == 0) {
#pragma unroll
            for (int r = 0; r < 8; ++r) acc[r] = 0.f;
        }
        const int aW = 2048 * c + 512 * g + q;
#pragma unroll
        for (int t = 0; t < 8; ++t) {
            int tg = (t + g) & 7;
            float4 xv[8];
#pragma unroll
            for (int r = 0; r < 8; ++r) xv[r] = xb[g * 64 + r * 8 + tg];
            int a0 = aW + 64 * tg;
            float w0 = Ws[(a0) ^ flip];
            float w1 = Ws[(a0 + 16) ^ flip];
            float w2 = Ws[(a0 + 32) ^ flip];
            float w3 = Ws[(a0 + 48) ^ flip];
#pragma unroll
            for (int r = 0; r < 8; ++r)
                acc[r] += xv[r].x * w0 + xv[r].y * w1 + xv[r].z * w2 + xv[r].w * w3;
        }
        if (issued < T) { stage(issued); ++issued; }
        if (c == 3) {
            int r0 = (first + (i >> 2) * stride) << 3;
#pragma unroll
            for (int r = 0; r < 8; ++r) {
                acc[r] += __shfl_xor(acc[r], 16);
                acc[r] += __shfl_xor(acc[r], 32);
            }
            float v0 = 0.f, v1 = 0.f;
#pragma unroll
            for (int r = 0; r < 4; ++r)
                if (g == r) { v0 = acc[r]; v1 = acc[r + 4]; }
            int row0 = r0 + g, row1 = r0 + 4 + g;
            if (row0 < n) {
                h1[(size_t)row0 * 16 + q] = v0;
                if (r1self) { float dv = dinv[row0]; r1self[(size_t)row0 * 16 + q] = v0 * dv * dv; }
            }
            if (row1 < n) {
                h1[(size_t)row1 * 16 + q] = v1;
                if (r1self) { float dv = dinv[row1]; r1self[(size_t)row1 * 16 + q] = v1 * dv * dv; }
            }
        }
    }
}

__global__ __launch_bounds__(256) void k_scatter16(const int* __restrict__ src,
                                                   const int* __restrict__ dst,
                                                   const float* __restrict__ feat,
                                                   const float* __restrict__ dinv,
                                                   float* __restrict__ outf, int total) {
    int t = blockIdx.x * 256 + threadIdx.x;
    if (t >= total) return;
    int e = t >> 4, k = t & 15;
    int s = src[e], d = dst[e];
    float w = dinv[s] * dinv[d];
    unsafeAtomicAdd(&outf[(size_t)d * 16 + k], feat[(size_t)s * 16 + k] * w);
}

__global__ __launch_bounds__(256) void k_relu16(float* __restrict__ r1,
                                                const float* __restrict__ b1, int total) {
    int t = blockIdx.x * 256 + threadIdx.x;
    if (t < total) r1[t] = fmaxf(r1[t] + b1[t & 15], 0.f);
}

__global__ __launch_bounds__(256) void k_self16(const float* __restrict__ feat,
                                                const float* __restrict__ dinv,
                                                float* __restrict__ outf, int total) {
    int t = blockIdx.x * 256 + threadIdx.x;
    if (t >= total) return;
    float dv = dinv[t >> 4];
    outf[t] = feat[t] * dv * dv;
}

__global__ __launch_bounds__(256) void k_out(const float* __restrict__ a,
                                             const float* __restrict__ W2,
                                             const float* __restrict__ b2,
                                             float* __restrict__ out, int n) {
    __shared__ float Ws[16 * 33];
    __shared__ float bs[32];
    for (int t = threadIdx.x; t < 512; t += 256) Ws[(t >> 5) * 33 + (t & 31)] = W2[t];
    if (threadIdx.x < 32) bs[threadIdx.x] = b2[threadIdx.x];
    __syncthreads();
    int t = blockIdx.x * 256 + threadIdx.x;
    int i = t >> 5, c = t & 31;
    if (i >= n) return;
    const float4* ar = reinterpret_cast<const float4*>(a + (size_t)i * 16);
    float acc = bs[c];
#pragma unroll
    for (int kk = 0; kk < 4; ++kk) {
        float4 v = ar[kk];
        acc += v.x * Ws[(4 * kk + 0) * 33 + c];
        acc += v.y * Ws[(4 * kk + 1) * 33 + c];
        acc += v.z * Ws[(4 * kk + 2) * 33 + c];
        acc += v.w * Ws[(4 * kk + 3) * 33 + c];
    }
    float m = acc;
#pragma unroll
    for (int o = 16; o > 0; o >>= 1) m = fmaxf(m, __shfl_xor(m, o, 32));
    float p = expf(acc - m);
#pragma unroll
    for (int o = 16; o > 0; o >>= 1) p += __shfl_xor(p, o, 32);
    out[t] = acc - m - logf(p);
}

extern "C" void kernel_launch(void* const* d_in, const int* in_sizes, int n_in,
                              void* d_out, int out_size, void* d_ws, size_t ws_size,
                              hipStream_t stream) {
    const float* x  = (const float*)d_in[0];
    const int* ei   = (const int*)d_in[1];
    const float* W1 = (const float*)d_in[2];
    const float* b1 = (const float*)d_in[3];
    const float* W2 = (const float*)d_in[4];
    const float* b2 = (const float*)d_in[5];
    float* out = (float*)d_out;

    const int n = in_sizes[0] / 512;
    const int E = in_sizes[1] / 2;
    const int* src = ei;
    const int* dst = ei + E;
    const int NB = (n + BK - 1) >> BKSH;
    const int gfill = (E + CHUNK - 1) / CHUNK;
    const int ntiles = (n + 15) >> 4;
    const int ggemm = (ntiles + 3) / 4;

    float* ws = (float*)d_ws;

    size_t u_dinv  = 0;
    size_t u_foffs = u_dinv + n;
    size_t u_nend  = u_foffs + n;
    size_t u_gcur  = u_nend + n;
    size_t u_gq    = u_gcur + NB;
    size_t u_gq2   = u_gq + (size_t)NB * SLAB;
    size_t u_h1    = u_gq2 + (size_t)NB * SLAB;
    size_t u_r1    = u_h1 + 16 * (size_t)n;
    size_t need    = (u_r1 + 16 * (size_t)n) * 4;

    if (ws_size >= need && NB <= MAXNB) {
        float* dinv = ws + u_dinv;
        int* offs   = (int*)(ws + u_foffs);
        int* nend   = (int*)(ws + u_nend);
        int* gcur   = (int*)(ws + u_gcur);
        int* gq     = (int*)(ws + u_gq);
        int* gq2    = (int*)(ws + u_gq2);
        unsigned short* gs1b = (unsigned short*)(ws + u_h1);
        unsigned short* r1sb = (unsigned short*)(ws + u_r1);

        k_init_cur<<<(NB + 255) / 256, 256, 0, stream>>>(gcur, NB);
        k_fill2   <<<gfill, 256, 0, stream>>>(src, dst, gcur, gq, E, NB);
        k_sortb   <<<NB, 256, 0, stream>>>(gq, gcur, gq2, offs, nend, dinv, n);
        k_gemm_mfma<<<ggemm, 256, 0, stream>>>(x, W1, dinv, gs1b, n);
        k_agg_b   <<<(n * 16 + 255) / 256, 256, 0, stream>>>(gs1b, gq2, offs, nend,
                                                             dinv, b1, r1sb, n);
        k_agg_out <<<(n * 16 + 255) / 256, 256, 0, stream>>>(r1sb, gq2, offs, nend,
                                                             dinv, W2, b2, out, n);
    } else {
        float* dinv = ws;
        float* h1   = ws + n;
        float* r1   = ws + n + 16 * (size_t)n;
        int* cnt    = (int*)h1;
        float* agg2r = h1;

        const int total1 = E * 16;
        k_zero_i   <<<(n + 255) / 256, 256, 0, stream>>>(cnt, n);
        k_count    <<<(E + 255) / 256, 256, 0, stream>>>(dst, cnt, E);
        k_dinv     <<<(n + 255) / 256, 256, 0, stream>>>(cnt, dinv, n);
        k_gemm1    <<<1024, 256, 0, stream>>>(x, W1, dinv, h1, r1, n);
        k_scatter16<<<(total1 + 255) / 256, 256, 0, stream>>>(src, dst, h1, dinv, r1, total1);
        k_relu16   <<<(n * 16 + 255) / 256, 256, 0, stream>>>(r1, b1, n * 16);
        k_self16   <<<(n * 16 + 255) / 256, 256, 0, stream>>>(r1, dinv, agg2r, n * 16);
        k_scatter16<<<(total1 + 255) / 256, 256, 0, stream>>>(src, dst, r1, dinv, agg2r, total1);
        k_out      <<<(n * 32 + 255) / 256, 256, 0, stream>>>(agg2r, W2, b2, out, n);
    }
}